// Round 1
// baseline (4455.828 us; speedup 1.0000x reference)
//
#include <hip/hip_runtime.h>
#include <hip/hip_bf16.h>

#define N_NODES 50000
#define N_EDGES 600000
#define N_GRAPHS 256
#define C 128

// ---------------------------------------------------------------- degree
__global__ void k_deg(const int* __restrict__ tgt, int* __restrict__ deg) {
    int e = blockIdx.x * blockDim.x + threadIdx.x;
    if (e < N_EDGES) atomicAdd(&deg[tgt[e]], 1);
}

__global__ void k_deginv(float* __restrict__ deg) {
    int n = blockIdx.x * blockDim.x + threadIdx.x;
    if (n >= N_NODES) return;
    int c = ((const int*)deg)[n];
    deg[n] = 1.0f / fmaxf((float)c, 1.0f);
}

// ---------------------------------------------------------------- scatter-add (mean numerator)
// one thread per (edge, 4-channel group): coalesced float4 gather, 4 f32 HW atomics
__global__ __launch_bounds__(256) void k_scatter(const float* __restrict__ h,
                                                 const int* __restrict__ src,
                                                 const int* __restrict__ tgt,
                                                 float* __restrict__ agg) {
    int t = blockIdx.x * 256 + threadIdx.x;
    int e = t >> 5;
    if (e >= N_EDGES) return;
    int c4 = (t & 31) << 2;
    int s = src[e], d = tgt[e];
    const float4 v = *(const float4*)(h + (size_t)s * C + c4);
    float* p = agg + (size_t)d * C + c4;
    unsafeAtomicAdd(p + 0, v.x);
    unsafeAtomicAdd(p + 1, v.y);
    unsafeAtomicAdd(p + 2, v.z);
    unsafeAtomicAdd(p + 3, v.w);
}

// ---------------------------------------------------------------- fused SAGE layer GEMM
// out[m][n] = relu( (agg[m]*dinv[m]) @ wl[n].T + hin[m] @ wr[n].T + bl[n] )
// K=256 concat GEMM: BM=64, BN=128 (full), BK=32; 256 threads, 8x4 per-thread tile.
#define GBM 64
#define GBK 32
__global__ __launch_bounds__(256) void k_sage_gemm(const float* __restrict__ agg,
                                                   const float* __restrict__ dinv,
                                                   const float* __restrict__ hin,
                                                   const float* __restrict__ wl,
                                                   const float* __restrict__ bl,
                                                   const float* __restrict__ wr,
                                                   float* __restrict__ hout) {
    __shared__ float As[GBK][GBM + 4];   // +4 keeps 16B alignment, breaks pow2 stride
    __shared__ float Bs[GBK][C + 4];
    const int tid = threadIdx.x;
    const int tx = tid & 31;   // cols tx*4 .. tx*4+3
    const int ty = tid >> 5;   // rows ty*8 .. ty*8+7
    const int m0 = blockIdx.x * GBM;

    float acc[8][4];
#pragma unroll
    for (int i = 0; i < 8; i++)
#pragma unroll
        for (int j = 0; j < 4; j++) acc[i][j] = 0.f;

    for (int k0 = 0; k0 < 256; k0 += GBK) {
        const bool isAgg = (k0 < 128);
        const float* Asrc = isAgg ? agg : hin;
        const float* W = isAgg ? wl : wr;
        const int ko = k0 & 127;
        __syncthreads();
        // A tile: 64 rows x 32 k = 512 float4, 2 per thread, stored transposed
#pragma unroll
        for (int i = 0; i < 2; i++) {
            int j = tid + i * 256;
            int m = j >> 3, kq = j & 7;
            int gm = m0 + m;
            int gmc = gm < N_NODES ? gm : N_NODES - 1;
            float4 v = *(const float4*)(Asrc + (size_t)gmc * C + ko + kq * 4);
            if (isAgg) {
                float s = dinv[gmc];
                v.x *= s; v.y *= s; v.z *= s; v.w *= s;
            }
            As[kq * 4 + 0][m] = v.x;
            As[kq * 4 + 1][m] = v.y;
            As[kq * 4 + 2][m] = v.z;
            As[kq * 4 + 3][m] = v.w;
        }
        // B tile: 128 n x 32 k = 1024 float4, 4 per thread, stored transposed
#pragma unroll
        for (int i = 0; i < 4; i++) {
            int j = tid + i * 256;
            int n = j >> 3, kq = j & 7;
            float4 v = *(const float4*)(W + n * C + ko + kq * 4);
            Bs[kq * 4 + 0][n] = v.x;
            Bs[kq * 4 + 1][n] = v.y;
            Bs[kq * 4 + 2][n] = v.z;
            Bs[kq * 4 + 3][n] = v.w;
        }
        __syncthreads();
#pragma unroll
        for (int kk = 0; kk < GBK; kk++) {
            float a[8], b[4];
            *(float4*)(a) = *(const float4*)&As[kk][ty * 8];
            *(float4*)(a + 4) = *(const float4*)&As[kk][ty * 8 + 4];
            *(float4*)(b) = *(const float4*)&Bs[kk][tx * 4];
#pragma unroll
            for (int im = 0; im < 8; im++)
#pragma unroll
                for (int in = 0; in < 4; in++)
                    acc[im][in] = fmaf(a[im], b[in], acc[im][in]);
        }
    }
    // epilogue: bias + relu, float4 stores (in-place safe: block only writes its own rows)
    float4 bias = *(const float4*)(bl + tx * 4);
#pragma unroll
    for (int im = 0; im < 8; im++) {
        int gm = m0 + ty * 8 + im;
        if (gm < N_NODES) {
            float4 o;
            o.x = fmaxf(acc[im][0] + bias.x, 0.f);
            o.y = fmaxf(acc[im][1] + bias.y, 0.f);
            o.z = fmaxf(acc[im][2] + bias.z, 0.f);
            o.w = fmaxf(acc[im][3] + bias.w, 0.f);
            *(float4*)(hout + (size_t)gm * C + tx * 4) = o;
        }
    }
}

// ---------------------------------------------------------------- graph segment boundaries (batch is sorted)
__global__ void k_gstart(const int* __restrict__ batch, int* __restrict__ gstart) {
    int g = blockIdx.x * blockDim.x + threadIdx.x;
    if (g > N_GRAPHS) return;
    int lo = 0, hi = N_NODES;
    while (lo < hi) {
        int mid = (lo + hi) >> 1;
        if (batch[mid] < g) lo = mid + 1;
        else hi = mid;
    }
    gstart[g] = lo;
}

// ---------------------------------------------------------------- mean pool per graph
__global__ __launch_bounds__(512) void k_pool(const float* __restrict__ h,
                                              const int* __restrict__ gstart,
                                              float* __restrict__ gmean) {
    __shared__ float part[4][C];
    int g = blockIdx.x;
    int c = threadIdx.x & 127, p = threadIdx.x >> 7;
    int s = gstart[g], e = gstart[g + 1];
    float sum = 0.f;
    for (int n = s + p; n < e; n += 4) sum += h[(size_t)n * C + c];
    part[p][c] = sum;
    __syncthreads();
    if (p == 0) {
        float tot = part[0][c] + part[1][c] + part[2][c] + part[3][c];
        float cnt = fmaxf((float)(e - s), 1.0f);
        gmean[g * C + c] = tot / cnt;
    }
}

// ---------------------------------------------------------------- classifier head
__global__ __launch_bounds__(256) void k_final(const float* __restrict__ h,
                                               const float* __restrict__ gmean,
                                               const int* __restrict__ root,
                                               const float* __restrict__ wcls,
                                               const float* __restrict__ bcls,
                                               float* __restrict__ out) {
    __shared__ float red[8];
    int g = blockIdx.x, t = threadIdx.x;
    float v;
    if (t < 128) v = h[(size_t)root[g] * C + t];
    else v = gmean[g * C + (t - 128)];
    float p0 = v * wcls[t];
    float p1 = v * wcls[256 + t];
#pragma unroll
    for (int off = 32; off; off >>= 1) {
        p0 += __shfl_down(p0, off);
        p1 += __shfl_down(p1, off);
    }
    int wid = t >> 6;
    if ((t & 63) == 0) { red[wid] = p0; red[4 + wid] = p1; }
    __syncthreads();
    if (t == 0) {
        out[g * 2 + 0] = red[0] + red[1] + red[2] + red[3] + bcls[0];
        out[g * 2 + 1] = red[4] + red[5] + red[6] + red[7] + bcls[1];
    }
}

// ---------------------------------------------------------------- launch
extern "C" void kernel_launch(void* const* d_in, const int* in_sizes, int n_in,
                              void* d_out, int out_size, void* d_ws, size_t ws_size,
                              hipStream_t stream) {
    const float* x = (const float*)d_in[0];
    const int* ei = (const int*)d_in[1];
    const int* src = ei;
    const int* tgt = ei + N_EDGES;
    const int* root = (const int*)d_in[2];
    const int* batch = (const int*)d_in[3];
    const float* wl[4] = {(const float*)d_in[4], (const float*)d_in[7],
                          (const float*)d_in[10], (const float*)d_in[13]};
    const float* blv[4] = {(const float*)d_in[5], (const float*)d_in[8],
                           (const float*)d_in[11], (const float*)d_in[14]};
    const float* wr[4] = {(const float*)d_in[6], (const float*)d_in[9],
                          (const float*)d_in[12], (const float*)d_in[15]};
    const float* wcls = (const float*)d_in[16];
    const float* bcls = (const float*)d_in[17];
    float* out = (float*)d_out;

    // workspace carve-up (all 16B aligned)
    float* h = (float*)d_ws;                        // 50000*128
    float* agg = h + (size_t)N_NODES * C;           // 50000*128
    float* degw = agg + (size_t)N_NODES * C;        // 50000 (int counts, then float inv)
    float* gmean = degw + 50000;                    // 256*128
    int* gstart = (int*)(gmean + N_GRAPHS * C);     // 257

    hipMemsetAsync(degw, 0, N_NODES * sizeof(int), stream);
    k_deg<<<(N_EDGES + 255) / 256, 256, 0, stream>>>(tgt, (int*)degw);
    k_deginv<<<(N_NODES + 255) / 256, 256, 0, stream>>>(degw);
    k_gstart<<<1, 512, 0, stream>>>(batch, gstart);

    const float* hin = x;
    for (int l = 0; l < 4; l++) {
        hipMemsetAsync(agg, 0, (size_t)N_NODES * C * sizeof(float), stream);
        k_scatter<<<(N_EDGES * 32) / 256, 256, 0, stream>>>(hin, src, tgt, agg);
        k_sage_gemm<<<(N_NODES + GBM - 1) / GBM, 256, 0, stream>>>(
            agg, degw, hin, wl[l], blv[l], wr[l], h);
        hin = h;
    }
    k_pool<<<N_GRAPHS, 512, 0, stream>>>(h, gstart, gmean);
    k_final<<<N_GRAPHS, 256, 0, stream>>>(h, gmean, root, wcls, bcls, out);
}

// Round 2
// 662.258 us; speedup vs baseline: 6.7282x; 6.7282x over previous
//
#include <hip/hip_runtime.h>
#include <hip/hip_bf16.h>

#define N_NODES 50000
#define N_EDGES 600000
#define N_GRAPHS 256
#define C 128

// ---------------------------------------------------------------- degree histogram
__global__ void k_deg(const int* __restrict__ tgt, int* __restrict__ deg) {
    int e = blockIdx.x * blockDim.x + threadIdx.x;
    if (e < N_EDGES) atomicAdd(&deg[tgt[e]], 1);
}

__global__ void k_deginv(const int* __restrict__ deg, float* __restrict__ dinv) {
    int n = blockIdx.x * blockDim.x + threadIdx.x;
    if (n >= N_NODES) return;
    dinv[n] = 1.0f / fmaxf((float)deg[n], 1.0f);
}

// ---------------------------------------------------------------- exclusive scan of deg -> rowptr (single block, chunked Hillis-Steele)
__global__ __launch_bounds__(1024) void k_scan(const int* __restrict__ deg, int* __restrict__ rowptr) {
    __shared__ int buf[1024];
    __shared__ int carry;
    const int tid = threadIdx.x;
    if (tid == 0) carry = 0;
    __syncthreads();
    for (int base = 0; base < N_NODES; base += 1024) {
        int v = (base + tid < N_NODES) ? deg[base + tid] : 0;
        buf[tid] = v;
        __syncthreads();
#pragma unroll
        for (int off = 1; off < 1024; off <<= 1) {
            int t = (tid >= off) ? buf[tid - off] : 0;
            __syncthreads();
            buf[tid] += t;
            __syncthreads();
        }
        int incl = buf[tid];
        int c = carry;
        if (base + tid < N_NODES) rowptr[base + tid] = c + incl - v;
        __syncthreads();                      // everyone has read carry
        if (tid == 0) carry = c + buf[1023];
        __syncthreads();                      // carry updated before buf reused
    }
    if (tid == 0) rowptr[N_NODES] = carry;
}

// ---------------------------------------------------------------- CSR fill (edges bucketed by target)
__global__ void k_fill(const int* __restrict__ src, const int* __restrict__ tgt,
                       const int* __restrict__ rowptr, int* __restrict__ fill,
                       int* __restrict__ csr_src) {
    int e = blockIdx.x * blockDim.x + threadIdx.x;
    if (e >= N_EDGES) return;
    int d = tgt[e];
    int pos = atomicAdd(&fill[d], 1);
    csr_src[rowptr[d] + pos] = src[e];
}

// ---------------------------------------------------------------- gather-mean (atomic-free): 32 lanes per node, float4/lane
__global__ __launch_bounds__(256) void k_gather(const float* __restrict__ h,
                                                const int* __restrict__ csr_src,
                                                const int* __restrict__ rowptr,
                                                const float* __restrict__ dinv,
                                                float* __restrict__ agg) {
    int node = blockIdx.x * 8 + (threadIdx.x >> 5);
    if (node >= N_NODES) return;
    int lane = threadIdx.x & 31;
    int s = rowptr[node], e = rowptr[node + 1];
    float4 acc = {0.f, 0.f, 0.f, 0.f};
    int j = s;
    for (; j + 1 < e; j += 2) {               // 2-edge unroll for ILP
        int s0 = csr_src[j], s1 = csr_src[j + 1];
        float4 v0 = *(const float4*)(h + (size_t)s0 * C + lane * 4);
        float4 v1 = *(const float4*)(h + (size_t)s1 * C + lane * 4);
        acc.x += v0.x + v1.x; acc.y += v0.y + v1.y;
        acc.z += v0.z + v1.z; acc.w += v0.w + v1.w;
    }
    if (j < e) {
        int s0 = csr_src[j];
        float4 v0 = *(const float4*)(h + (size_t)s0 * C + lane * 4);
        acc.x += v0.x; acc.y += v0.y; acc.z += v0.z; acc.w += v0.w;
    }
    float sc = dinv[node];
    float4 o = {acc.x * sc, acc.y * sc, acc.z * sc, acc.w * sc};
    *(float4*)(agg + (size_t)node * C + lane * 4) = o;
}

// ---------------------------------------------------------------- fused SAGE layer GEMM
// out[m][n] = relu( agg[m] @ wl[n].T + hin[m] @ wr[n].T + bl[n] )   (agg pre-scaled by dinv)
#define GBM 64
#define GBK 32
__global__ __launch_bounds__(256) void k_sage_gemm(const float* __restrict__ agg,
                                                   const float* __restrict__ hin,
                                                   const float* __restrict__ wl,
                                                   const float* __restrict__ bl,
                                                   const float* __restrict__ wr,
                                                   float* __restrict__ hout) {
    __shared__ float As[GBK][GBM + 4];
    __shared__ float Bs[GBK][C + 4];
    const int tid = threadIdx.x;
    const int tx = tid & 31;   // cols tx*4 .. tx*4+3
    const int ty = tid >> 5;   // rows ty*8 .. ty*8+7
    const int m0 = blockIdx.x * GBM;

    float acc[8][4];
#pragma unroll
    for (int i = 0; i < 8; i++)
#pragma unroll
        for (int j = 0; j < 4; j++) acc[i][j] = 0.f;

    for (int k0 = 0; k0 < 256; k0 += GBK) {
        const bool isAgg = (k0 < 128);
        const float* Asrc = isAgg ? agg : hin;
        const float* W = isAgg ? wl : wr;
        const int ko = k0 & 127;
        __syncthreads();
#pragma unroll
        for (int i = 0; i < 2; i++) {
            int j = tid + i * 256;
            int m = j >> 3, kq = j & 7;
            int gm = m0 + m;
            int gmc = gm < N_NODES ? gm : N_NODES - 1;
            float4 v = *(const float4*)(Asrc + (size_t)gmc * C + ko + kq * 4);
            As[kq * 4 + 0][m] = v.x;
            As[kq * 4 + 1][m] = v.y;
            As[kq * 4 + 2][m] = v.z;
            As[kq * 4 + 3][m] = v.w;
        }
#pragma unroll
        for (int i = 0; i < 4; i++) {
            int j = tid + i * 256;
            int n = j >> 3, kq = j & 7;
            float4 v = *(const float4*)(W + n * C + ko + kq * 4);
            Bs[kq * 4 + 0][n] = v.x;
            Bs[kq * 4 + 1][n] = v.y;
            Bs[kq * 4 + 2][n] = v.z;
            Bs[kq * 4 + 3][n] = v.w;
        }
        __syncthreads();
#pragma unroll
        for (int kk = 0; kk < GBK; kk++) {
            float a[8], b[4];
            *(float4*)(a) = *(const float4*)&As[kk][ty * 8];
            *(float4*)(a + 4) = *(const float4*)&As[kk][ty * 8 + 4];
            *(float4*)(b) = *(const float4*)&Bs[kk][tx * 4];
#pragma unroll
            for (int im = 0; im < 8; im++)
#pragma unroll
                for (int in = 0; in < 4; in++)
                    acc[im][in] = fmaf(a[im], b[in], acc[im][in]);
        }
    }
    float4 bias = *(const float4*)(bl + tx * 4);
#pragma unroll
    for (int im = 0; im < 8; im++) {
        int gm = m0 + ty * 8 + im;
        if (gm < N_NODES) {
            float4 o;
            o.x = fmaxf(acc[im][0] + bias.x, 0.f);
            o.y = fmaxf(acc[im][1] + bias.y, 0.f);
            o.z = fmaxf(acc[im][2] + bias.z, 0.f);
            o.w = fmaxf(acc[im][3] + bias.w, 0.f);
            *(float4*)(hout + (size_t)gm * C + tx * 4) = o;
        }
    }
}

// ---------------------------------------------------------------- graph segment boundaries (batch is sorted)
__global__ void k_gstart(const int* __restrict__ batch, int* __restrict__ gstart) {
    int g = blockIdx.x * blockDim.x + threadIdx.x;
    if (g > N_GRAPHS) return;
    int lo = 0, hi = N_NODES;
    while (lo < hi) {
        int mid = (lo + hi) >> 1;
        if (batch[mid] < g) lo = mid + 1;
        else hi = mid;
    }
    gstart[g] = lo;
}

// ---------------------------------------------------------------- mean pool per graph
__global__ __launch_bounds__(512) void k_pool(const float* __restrict__ h,
                                              const int* __restrict__ gstart,
                                              float* __restrict__ gmean) {
    __shared__ float part[4][C];
    int g = blockIdx.x;
    int c = threadIdx.x & 127, p = threadIdx.x >> 7;
    int s = gstart[g], e = gstart[g + 1];
    float sum = 0.f;
    for (int n = s + p; n < e; n += 4) sum += h[(size_t)n * C + c];
    part[p][c] = sum;
    __syncthreads();
    if (p == 0) {
        float tot = part[0][c] + part[1][c] + part[2][c] + part[3][c];
        float cnt = fmaxf((float)(e - s), 1.0f);
        gmean[g * C + c] = tot / cnt;
    }
}

// ---------------------------------------------------------------- classifier head
__global__ __launch_bounds__(256) void k_final(const float* __restrict__ h,
                                               const float* __restrict__ gmean,
                                               const int* __restrict__ root,
                                               const float* __restrict__ wcls,
                                               const float* __restrict__ bcls,
                                               float* __restrict__ out) {
    __shared__ float red[8];
    int g = blockIdx.x, t = threadIdx.x;
    float v;
    if (t < 128) v = h[(size_t)root[g] * C + t];
    else v = gmean[g * C + (t - 128)];
    float p0 = v * wcls[t];
    float p1 = v * wcls[256 + t];
#pragma unroll
    for (int off = 32; off; off >>= 1) {
        p0 += __shfl_down(p0, off);
        p1 += __shfl_down(p1, off);
    }
    int wid = t >> 6;
    if ((t & 63) == 0) { red[wid] = p0; red[4 + wid] = p1; }
    __syncthreads();
    if (t == 0) {
        out[g * 2 + 0] = red[0] + red[1] + red[2] + red[3] + bcls[0];
        out[g * 2 + 1] = red[4] + red[5] + red[6] + red[7] + bcls[1];
    }
}

// ---------------------------------------------------------------- launch
extern "C" void kernel_launch(void* const* d_in, const int* in_sizes, int n_in,
                              void* d_out, int out_size, void* d_ws, size_t ws_size,
                              hipStream_t stream) {
    const float* x = (const float*)d_in[0];
    const int* ei = (const int*)d_in[1];
    const int* src = ei;
    const int* tgt = ei + N_EDGES;
    const int* root = (const int*)d_in[2];
    const int* batch = (const int*)d_in[3];
    const float* wl[4] = {(const float*)d_in[4], (const float*)d_in[7],
                          (const float*)d_in[10], (const float*)d_in[13]};
    const float* blv[4] = {(const float*)d_in[5], (const float*)d_in[8],
                           (const float*)d_in[11], (const float*)d_in[14]};
    const float* wr[4] = {(const float*)d_in[6], (const float*)d_in[9],
                          (const float*)d_in[12], (const float*)d_in[15]};
    const float* wcls = (const float*)d_in[16];
    const float* bcls = (const float*)d_in[17];
    float* out = (float*)d_out;

    // workspace carve-up (all 16B aligned)
    float* h = (float*)d_ws;                          // 50000*128 f
    float* agg = h + (size_t)N_NODES * C;             // 50000*128 f
    int* deg = (int*)(agg + (size_t)N_NODES * C);     // 50000 i
    float* dinv = (float*)(deg + N_NODES);            // 50000 f
    int* rowptr = (int*)(dinv + N_NODES);             // 50001 i
    int* fill = rowptr + N_NODES + 4;                 // 50000 i
    int* csr_src = fill + N_NODES;                    // 600000 i
    float* gmean = (float*)(csr_src + N_EDGES);       // 256*128 f
    int* gstart = (int*)(gmean + N_GRAPHS * C);       // 257 i

    hipMemsetAsync(deg, 0, N_NODES * sizeof(int), stream);
    hipMemsetAsync(fill, 0, N_NODES * sizeof(int), stream);
    k_deg<<<(N_EDGES + 255) / 256, 256, 0, stream>>>(tgt, deg);
    k_deginv<<<(N_NODES + 255) / 256, 256, 0, stream>>>(deg, dinv);
    k_scan<<<1, 1024, 0, stream>>>(deg, rowptr);
    k_fill<<<(N_EDGES + 255) / 256, 256, 0, stream>>>(src, tgt, rowptr, fill, csr_src);
    k_gstart<<<1, 512, 0, stream>>>(batch, gstart);

    const float* hin = x;
    for (int l = 0; l < 4; l++) {
        k_gather<<<(N_NODES + 7) / 8, 256, 0, stream>>>(hin, csr_src, rowptr, dinv, agg);
        k_sage_gemm<<<(N_NODES + GBM - 1) / GBM, 256, 0, stream>>>(
            agg, hin, wl[l], blv[l], wr[l], h);
        hin = h;
    }
    k_pool<<<N_GRAPHS, 512, 0, stream>>>(h, gstart, gmean);
    k_final<<<N_GRAPHS, 256, 0, stream>>>(h, gmean, root, wcls, bcls, out);
}